// Round 1
// baseline (326.380 us; speedup 1.0000x reference)
//
#include <hip/hip_runtime.h>
#include <cstdint>

#define IN_FEAT 256
#define OUT_FEAT 64

constexpr int ROWS_PER_WAVE = 16;   // gemm register tile (rows per wave)
constexpr int EPW = 128;            // edges per wave in scatter

// ---------------------------------------------------------------------------
// Kernel 1: proj[n_rows][64] = feat[n_rows][256] @ W[256][64]   (all fp32)
// Block = 256 threads = 4 waves. W staged in LDS (64 KB). Each wave computes
// a 16-row x 64-col tile: lane = output column, acc[16] in registers.
// W LDS reads amortized over 16 rows; feat read once via 16B broadcast loads.
// ---------------------------------------------------------------------------
__global__ __launch_bounds__(256) void gemm_proj(
    const float* __restrict__ feat, const float* __restrict__ W,
    float* __restrict__ proj, int n_rows)
{
    __shared__ float sW[IN_FEAT * OUT_FEAT];  // 64 KB
    #pragma unroll
    for (int i = 0; i < (IN_FEAT * OUT_FEAT) / 256; ++i)
        sW[i * 256 + threadIdx.x] = W[i * 256 + threadIdx.x];
    __syncthreads();

    const int lane = threadIdx.x & 63;
    const int wave = threadIdx.x >> 6;
    const int row0 = blockIdx.x * (ROWS_PER_WAVE * 4) + wave * ROWS_PER_WAVE;
    if (row0 >= n_rows) return;

    float acc[ROWS_PER_WAVE];
    #pragma unroll
    for (int r = 0; r < ROWS_PER_WAVE; ++r) acc[r] = 0.f;

    if (row0 + ROWS_PER_WAVE <= n_rows) {
        // fast path: full 16-row tile
        for (int k4 = 0; k4 < IN_FEAT / 4; ++k4) {
            // sW[k][lane]: 64 lanes span 256B -> 2 lanes/bank, conflict-free
            const float w0 = sW[(k4 * 4 + 0) * OUT_FEAT + lane];
            const float w1 = sW[(k4 * 4 + 1) * OUT_FEAT + lane];
            const float w2 = sW[(k4 * 4 + 2) * OUT_FEAT + lane];
            const float w3 = sW[(k4 * 4 + 3) * OUT_FEAT + lane];
            #pragma unroll
            for (int r = 0; r < ROWS_PER_WAVE; ++r) {
                const float4 f = *reinterpret_cast<const float4*>(
                    feat + (size_t)(row0 + r) * IN_FEAT + k4 * 4);
                acc[r] = fmaf(f.x, w0, acc[r]);
                acc[r] = fmaf(f.y, w1, acc[r]);
                acc[r] = fmaf(f.z, w2, acc[r]);
                acc[r] = fmaf(f.w, w3, acc[r]);
            }
        }
        #pragma unroll
        for (int r = 0; r < ROWS_PER_WAVE; ++r)
            proj[(size_t)(row0 + r) * OUT_FEAT + lane] = acc[r];
    } else {
        // tail path (not hit for n_rows % 16 == 0, kept for safety);
        // bounds check inside unrolled loop keeps acc[] statically indexed
        for (int k4 = 0; k4 < IN_FEAT / 4; ++k4) {
            const float w0 = sW[(k4 * 4 + 0) * OUT_FEAT + lane];
            const float w1 = sW[(k4 * 4 + 1) * OUT_FEAT + lane];
            const float w2 = sW[(k4 * 4 + 2) * OUT_FEAT + lane];
            const float w3 = sW[(k4 * 4 + 3) * OUT_FEAT + lane];
            #pragma unroll
            for (int r = 0; r < ROWS_PER_WAVE; ++r) {
                if (row0 + r < n_rows) {
                    const float4 f = *reinterpret_cast<const float4*>(
                        feat + (size_t)(row0 + r) * IN_FEAT + k4 * 4);
                    acc[r] = fmaf(f.x, w0, acc[r]);
                    acc[r] = fmaf(f.y, w1, acc[r]);
                    acc[r] = fmaf(f.z, w2, acc[r]);
                    acc[r] = fmaf(f.w, w3, acc[r]);
                }
            }
        }
        #pragma unroll
        for (int r = 0; r < ROWS_PER_WAVE; ++r)
            if (row0 + r < n_rows)
                proj[(size_t)(row0 + r) * OUT_FEAT + lane] = acc[r];
    }
}

// ---------------------------------------------------------------------------
// Kernel 2: out[row] += val * proj[col]  over sorted-by-row COO edges.
// One wave owns EPW contiguous edges; lane = feature column (0..63).
// Runs of equal row accumulate in a register; flush = one coalesced
// 64-lane atomicAdd per (row, wave) segment (~113k flushes total).
// rows/cols/vals loads are wave-uniform (broadcast); branch is uniform.
// ---------------------------------------------------------------------------
__global__ __launch_bounds__(256) void gather_scatter(
    const float* __restrict__ proj, const int* __restrict__ rows,
    const int* __restrict__ cols, const float* __restrict__ vals,
    float* __restrict__ out, int n_edges)
{
    const int lane = threadIdx.x & 63;
    const long wid = (long)((blockIdx.x * 256 + threadIdx.x) >> 6);
    const long e0 = wid * EPW;
    if (e0 >= n_edges) return;
    const long e1 = min(e0 + (long)EPW, (long)n_edges);

    int cur = rows[e0];
    float acc = 0.f;
    #pragma unroll 4
    for (long e = e0; e < e1; ++e) {
        const int   r = rows[e];
        const int   c = cols[e];
        const float v = vals[e];
        const float p = proj[(size_t)c * OUT_FEAT + lane];
        if (r != cur) {                       // wave-uniform branch
            atomicAdd(out + (size_t)cur * OUT_FEAT + lane, acc);
            acc = 0.f;
            cur = r;
        }
        acc = fmaf(v, p, acc);
    }
    atomicAdd(out + (size_t)cur * OUT_FEAT + lane, acc);
}

extern "C" void kernel_launch(void* const* d_in, const int* in_sizes, int n_in,
                              void* d_out, int out_size, void* d_ws, size_t ws_size,
                              hipStream_t stream)
{
    const float* feat     = (const float*)d_in[0];
    const float* weight   = (const float*)d_in[1];
    const int*   adj_rows = (const int*)d_in[2];
    const int*   adj_cols = (const int*)d_in[3];
    const float* adj_vals = (const float*)d_in[4];
    float*       out      = (float*)d_out;
    float*       proj     = (float*)d_ws;   // n_nodes*64*4 = 25.6 MB scratch

    const int n_nodes = in_sizes[0] / IN_FEAT;   // 100000
    const int n_edges = in_sizes[2];             // 1600000

    // out is poisoned 0xAA and nodes without edges must be 0 -> zero it
    hipMemsetAsync(d_out, 0, (size_t)out_size * sizeof(float), stream);

    const int gemm_blocks = (n_nodes + ROWS_PER_WAVE * 4 - 1) / (ROWS_PER_WAVE * 4);
    gemm_proj<<<gemm_blocks, 256, 0, stream>>>(feat, weight, proj, n_nodes);

    const int waves  = (n_edges + EPW - 1) / EPW;
    const int blocks = (waves + 3) / 4;
    gather_scatter<<<blocks, 256, 0, stream>>>(proj, adj_rows, adj_cols,
                                               adj_vals, out, n_edges);
}

// Round 2
// 164.716 us; speedup vs baseline: 1.9815x; 1.9815x over previous
//
#include <hip/hip_runtime.h>
#include <cstdint>

#define IN_FEAT 256
#define OUT_FEAT 64

constexpr int EPW = 128;            // edges per wave in scatter

typedef __attribute__((ext_vector_type(4))) float f32x4;
typedef __attribute__((ext_vector_type(8))) __bf16 bf16x8;

union BF8 { unsigned short u[8]; bf16x8 v; };

__device__ inline unsigned short f2bf(float f) {   // fp32 -> bf16 bits, RNE
    unsigned u = __builtin_bit_cast(unsigned, f);
    unsigned r = u + 0x7fffu + ((u >> 16) & 1u);
    return (unsigned short)(r >> 16);
}
__device__ inline float bf2f(unsigned short h) {
    return __builtin_bit_cast(float, (unsigned)h << 16);
}

// ---------------------------------------------------------------------------
// Kernel 1: proj = feat @ W via mfma_f32_16x16x32_bf16.
// feat split hi/lo bf16 (2 MFMAs) -> feat quantization error cancels;
// W single bf16 staged in LDS, pre-packed into B-fragment layout:
//   B frag: lane l holds B[k = ks*32 + (l>>4)*8 + j][col = ct*16 + (l&15)]
// A frag:   lane l holds A[row = l&15][k = ks*32 + (l>>4)*8 + j]
// D:        lane l reg r -> D[row = (l>>4)*4 + r][col = l&15]   (m89-verified)
// Block = 256 thr = 4 waves, each wave one 16-row x 64-col tile.
// Each lane preloads its full feat row-chunk (16 dwordx4) for MLP.
// ---------------------------------------------------------------------------
__global__ __launch_bounds__(256) void gemm_proj_mfma(
    const float* __restrict__ feat, const float* __restrict__ W,
    float* __restrict__ proj, int n_rows)
{
    __shared__ unsigned short sWb[8 * 4 * 64 * 8];   // 16384 bf16 = 32 KB

    // Stage + convert + fragment-pack W (L2-hot after first blocks).
    for (int i = threadIdx.x; i < 8 * 4 * 64 * 8; i += 256) {
        const int j  = i & 7;
        const int l  = (i >> 3) & 63;
        const int ct = (i >> 9) & 3;
        const int ks = i >> 11;
        const int k  = ks * 32 + ((l >> 4) * 8) + j;
        const int c  = ct * 16 + (l & 15);
        sWb[i] = f2bf(W[k * OUT_FEAT + c]);
    }
    __syncthreads();

    const int lane = threadIdx.x & 63;
    const int wave = threadIdx.x >> 6;
    const int row0 = blockIdx.x * 64 + wave * 16;
    if (row0 >= n_rows) return;

    const int kgrp = lane >> 4;            // 0..3
    int ar = row0 + (lane & 15);           // this lane's A row
    if (ar >= n_rows) ar = n_rows - 1;     // clamp; results discarded on store

    // Preload full feat row-chunk: 8 k-steps x 32 B = 16 outstanding dwordx4.
    f32x4 fa[16];
    const float* fp = feat + (size_t)ar * IN_FEAT + kgrp * 8;
    #pragma unroll
    for (int ks = 0; ks < 8; ++ks) {
        fa[2 * ks]     = *reinterpret_cast<const f32x4*>(fp + ks * 32);
        fa[2 * ks + 1] = *reinterpret_cast<const f32x4*>(fp + ks * 32 + 4);
    }

    f32x4 acc[4];
    #pragma unroll
    for (int ct = 0; ct < 4; ++ct) acc[ct] = f32x4{0.f, 0.f, 0.f, 0.f};

    #pragma unroll
    for (int ks = 0; ks < 8; ++ks) {
        BF8 Ah, Al;
        #pragma unroll
        for (int h = 0; h < 2; ++h) {
            const f32x4 v = fa[2 * ks + h];
            #pragma unroll
            for (int j = 0; j < 4; ++j) {
                const float f = v[j];
                const unsigned short hb = f2bf(f);
                Ah.u[h * 4 + j] = hb;
                Al.u[h * 4 + j] = f2bf(f - bf2f(hb));
            }
        }
        #pragma unroll
        for (int ct = 0; ct < 4; ++ct) {
            BF8 B;
            B.v = *reinterpret_cast<const bf16x8*>(
                &sWb[((ks * 4 + ct) * 64 + lane) * 8]);
            acc[ct] = __builtin_amdgcn_mfma_f32_16x16x32_bf16(Ah.v, B.v, acc[ct], 0, 0, 0);
            acc[ct] = __builtin_amdgcn_mfma_f32_16x16x32_bf16(Al.v, B.v, acc[ct], 0, 0, 0);
        }
    }

    #pragma unroll
    for (int r = 0; r < 4; ++r) {
        const int row = row0 + kgrp * 4 + r;
        if (row < n_rows) {
            #pragma unroll
            for (int ct = 0; ct < 4; ++ct)
                proj[(size_t)row * OUT_FEAT + ct * 16 + (lane & 15)] = acc[ct][r];
        }
    }
}

// ---------------------------------------------------------------------------
// Kernel 2: out[row] += val * proj[col]  over sorted-by-row COO edges.
// One wave owns EPW contiguous edges; lane = feature column (0..63).
// Runs of equal row accumulate in a register; flush = one coalesced
// 64-lane atomicAdd per (row, wave) segment (~113k flushes total).
// ---------------------------------------------------------------------------
__global__ __launch_bounds__(256) void gather_scatter(
    const float* __restrict__ proj, const int* __restrict__ rows,
    const int* __restrict__ cols, const float* __restrict__ vals,
    float* __restrict__ out, int n_edges)
{
    const int lane = threadIdx.x & 63;
    const long wid = (long)((blockIdx.x * 256 + threadIdx.x) >> 6);
    const long e0 = wid * EPW;
    if (e0 >= n_edges) return;
    const long e1 = min(e0 + (long)EPW, (long)n_edges);

    int cur = rows[e0];
    float acc = 0.f;
    #pragma unroll 4
    for (long e = e0; e < e1; ++e) {
        const int   r = rows[e];
        const int   c = cols[e];
        const float v = vals[e];
        const float p = proj[(size_t)c * OUT_FEAT + lane];
        if (r != cur) {                       // wave-uniform branch
            atomicAdd(out + (size_t)cur * OUT_FEAT + lane, acc);
            acc = 0.f;
            cur = r;
        }
        acc = fmaf(v, p, acc);
    }
    atomicAdd(out + (size_t)cur * OUT_FEAT + lane, acc);
}

extern "C" void kernel_launch(void* const* d_in, const int* in_sizes, int n_in,
                              void* d_out, int out_size, void* d_ws, size_t ws_size,
                              hipStream_t stream)
{
    const float* feat     = (const float*)d_in[0];
    const float* weight   = (const float*)d_in[1];
    const int*   adj_rows = (const int*)d_in[2];
    const int*   adj_cols = (const int*)d_in[3];
    const float* adj_vals = (const float*)d_in[4];
    float*       out      = (float*)d_out;
    float*       proj     = (float*)d_ws;   // n_nodes*64*4 = 25.6 MB scratch

    const int n_nodes = in_sizes[0] / IN_FEAT;   // 100000
    const int n_edges = in_sizes[2];             // 1600000

    // out is poisoned 0xAA and nodes without edges must be 0 -> zero it
    hipMemsetAsync(d_out, 0, (size_t)out_size * sizeof(float), stream);

    const int gemm_blocks = (n_nodes + 63) / 64;
    gemm_proj_mfma<<<gemm_blocks, 256, 0, stream>>>(feat, weight, proj, n_nodes);

    const int waves  = (n_edges + EPW - 1) / EPW;
    const int blocks = (waves + 3) / 4;
    gather_scatter<<<blocks, 256, 0, stream>>>(proj, adj_rows, adj_cols,
                                               adj_vals, out, n_edges);
}

// Round 3
// 145.115 us; speedup vs baseline: 2.2491x; 1.1351x over previous
//
#include <hip/hip_runtime.h>
#include <cstdint>

#define IN_FEAT 256
#define OUT_FEAT 64

constexpr int EPW = 64;             // edges per wave in scatter (1 per lane)

typedef __attribute__((ext_vector_type(4))) float f32x4;
typedef __attribute__((ext_vector_type(8))) __bf16 bf16x8;

union BF8 { unsigned short u[8]; bf16x8 v; };

__device__ inline unsigned short f2bf(float f) {   // fp32 -> bf16 bits, RNE
    unsigned u = __builtin_bit_cast(unsigned, f);
    unsigned r = u + 0x7fffu + ((u >> 16) & 1u);
    return (unsigned short)(r >> 16);
}
__device__ inline float bf2f(unsigned short h) {
    return __builtin_bit_cast(float, (unsigned)h << 16);
}

// ---------------------------------------------------------------------------
// Kernel 1: proj = feat @ W via mfma_f32_16x16x32_bf16.
// feat split hi/lo bf16 (2 MFMAs) -> feat quantization error cancels;
// W single bf16 staged in LDS, pre-packed into B-fragment layout.
// Block = 256 thr = 4 waves, each wave one 16-row x 64-col tile.
// ---------------------------------------------------------------------------
__global__ __launch_bounds__(256) void gemm_proj_mfma(
    const float* __restrict__ feat, const float* __restrict__ W,
    float* __restrict__ proj, int n_rows)
{
    __shared__ unsigned short sWb[8 * 4 * 64 * 8];   // 16384 bf16 = 32 KB

    for (int i = threadIdx.x; i < 8 * 4 * 64 * 8; i += 256) {
        const int j  = i & 7;
        const int l  = (i >> 3) & 63;
        const int ct = (i >> 9) & 3;
        const int ks = i >> 11;
        const int k  = ks * 32 + ((l >> 4) * 8) + j;
        const int c  = ct * 16 + (l & 15);
        sWb[i] = f2bf(W[k * OUT_FEAT + c]);
    }
    __syncthreads();

    const int lane = threadIdx.x & 63;
    const int wave = threadIdx.x >> 6;
    const int row0 = blockIdx.x * 64 + wave * 16;
    if (row0 >= n_rows) return;

    const int kgrp = lane >> 4;            // 0..3
    int ar = row0 + (lane & 15);           // this lane's A row
    if (ar >= n_rows) ar = n_rows - 1;     // clamp; results discarded on store

    f32x4 fa[16];
    const float* fp = feat + (size_t)ar * IN_FEAT + kgrp * 8;
    #pragma unroll
    for (int ks = 0; ks < 8; ++ks) {
        fa[2 * ks]     = *reinterpret_cast<const f32x4*>(fp + ks * 32);
        fa[2 * ks + 1] = *reinterpret_cast<const f32x4*>(fp + ks * 32 + 4);
    }

    f32x4 acc[4];
    #pragma unroll
    for (int ct = 0; ct < 4; ++ct) acc[ct] = f32x4{0.f, 0.f, 0.f, 0.f};

    #pragma unroll
    for (int ks = 0; ks < 8; ++ks) {
        BF8 Ah, Al;
        #pragma unroll
        for (int h = 0; h < 2; ++h) {
            const f32x4 v = fa[2 * ks + h];
            #pragma unroll
            for (int j = 0; j < 4; ++j) {
                const float f = v[j];
                const unsigned short hb = f2bf(f);
                Ah.u[h * 4 + j] = hb;
                Al.u[h * 4 + j] = f2bf(f - bf2f(hb));
            }
        }
        #pragma unroll
        for (int ct = 0; ct < 4; ++ct) {
            BF8 B;
            B.v = *reinterpret_cast<const bf16x8*>(
                &sWb[((ks * 4 + ct) * 64 + lane) * 8]);
            acc[ct] = __builtin_amdgcn_mfma_f32_16x16x32_bf16(Ah.v, B.v, acc[ct], 0, 0, 0);
            acc[ct] = __builtin_amdgcn_mfma_f32_16x16x32_bf16(Al.v, B.v, acc[ct], 0, 0, 0);
        }
    }

    #pragma unroll
    for (int r = 0; r < 4; ++r) {
        const int row = row0 + kgrp * 4 + r;
        if (row < n_rows) {
            #pragma unroll
            for (int ct = 0; ct < 4; ++ct)
                proj[(size_t)row * OUT_FEAT + ct * 16 + (lane & 15)] = acc[ct][r];
        }
    }
}

// ---------------------------------------------------------------------------
// Kernel 2: out[row] += val * proj[col]  over sorted-by-row COO edges.
// One wave owns EPW=64 contiguous edges; lane = feature column.
// Metadata preloaded coalesced (lane i holds edge e0+i's r/c/v), then the
// edge loop is fully unrolled with readlane(.., imm) -> all gather addresses
// are SGPR-resident, 64 independent proj gathers issue back-to-back (MLP),
// row-change test is a scalar compare + uniform branch. Segmented register
// accumulation; one coalesced 64-lane atomicAdd per row-segment.
// ---------------------------------------------------------------------------
__global__ __launch_bounds__(256) void gather_scatter(
    const float* __restrict__ proj, const int* __restrict__ rows,
    const int* __restrict__ cols, const float* __restrict__ vals,
    float* __restrict__ out, int n_edges)
{
    const int lane = threadIdx.x & 63;
    const long wid = (long)((blockIdx.x * 256 + threadIdx.x) >> 6);
    const long e0 = wid * EPW;
    if (e0 >= n_edges) return;
    const int nE = (int)min((long)EPW, (long)n_edges - e0);

    // Coalesced metadata preload: lane i <- edge e0+i (guard tail lanes).
    int r_v = 0, c_v = 0; int v_bits = 0;
    if (lane < nE) {
        r_v    = rows[e0 + lane];
        c_v    = cols[e0 + lane];
        v_bits = __builtin_bit_cast(int, vals[e0 + lane]);
    }

    float acc = 0.f;
    int cur = __builtin_amdgcn_readlane(r_v, 0);

    #pragma unroll
    for (int i = 0; i < EPW; ++i) {
        if (i >= nE) break;                               // uniform
        const int   r = __builtin_amdgcn_readlane(r_v, i); // SGPR
        const int   c = __builtin_amdgcn_readlane(c_v, i); // SGPR
        const float v = __builtin_bit_cast(float, __builtin_amdgcn_readlane(v_bits, i));
        const float p = proj[(size_t)c * OUT_FEAT + lane]; // s-base + lane*4
        if (r != cur) {                                    // scalar, uniform
            atomicAdd(out + (size_t)cur * OUT_FEAT + lane, acc);
            acc = 0.f;
            cur = r;
        }
        acc = fmaf(v, p, acc);
    }
    atomicAdd(out + (size_t)cur * OUT_FEAT + lane, acc);
}

extern "C" void kernel_launch(void* const* d_in, const int* in_sizes, int n_in,
                              void* d_out, int out_size, void* d_ws, size_t ws_size,
                              hipStream_t stream)
{
    const float* feat     = (const float*)d_in[0];
    const float* weight   = (const float*)d_in[1];
    const int*   adj_rows = (const int*)d_in[2];
    const int*   adj_cols = (const int*)d_in[3];
    const float* adj_vals = (const float*)d_in[4];
    float*       out      = (float*)d_out;
    float*       proj     = (float*)d_ws;   // n_nodes*64*4 = 25.6 MB scratch

    const int n_nodes = in_sizes[0] / IN_FEAT;   // 100000
    const int n_edges = in_sizes[2];             // 1600000

    // out is poisoned 0xAA and nodes without edges must be 0 -> zero it
    hipMemsetAsync(d_out, 0, (size_t)out_size * sizeof(float), stream);

    const int gemm_blocks = (n_nodes + 63) / 64;
    gemm_proj_mfma<<<gemm_blocks, 256, 0, stream>>>(feat, weight, proj, n_nodes);

    const int waves  = (n_edges + EPW - 1) / EPW;
    const int blocks = (waves + 3) / 4;
    gather_scatter<<<blocks, 256, 0, stream>>>(proj, adj_rows, adj_cols,
                                               adj_vals, out, n_edges);
}

// Round 4
// 112.178 us; speedup vs baseline: 2.9095x; 1.2936x over previous
//
#include <hip/hip_runtime.h>
#include <cstdint>

#define IN_FEAT 256
#define OUT_FEAT 64

constexpr int EPW = 64;             // edges per wave in scatter (1 per lane)

typedef __attribute__((ext_vector_type(4))) float f32x4;
typedef __attribute__((ext_vector_type(8))) __bf16 bf16x8;

union BF8 { unsigned short u[8]; bf16x8 v; };

__device__ inline unsigned short f2bf(float f) {   // fp32 -> bf16 bits, RNE
    unsigned u = __builtin_bit_cast(unsigned, f);
    unsigned r = u + 0x7fffu + ((u >> 16) & 1u);
    return (unsigned short)(r >> 16);
}
__device__ inline float bf2f(unsigned short h) {
    return __builtin_bit_cast(float, (unsigned)h << 16);
}

// ---------------------------------------------------------------------------
// Kernel 1: proj = feat @ W via mfma_f32_16x16x32_bf16.
// feat split hi/lo bf16 (2 MFMAs) -> feat quantization error cancels;
// W single bf16 staged in LDS, pre-packed into B-fragment layout.
// Block = 256 thr = 4 waves, each wave one 16-row x 64-col tile.
// ---------------------------------------------------------------------------
__global__ __launch_bounds__(256) void gemm_proj_mfma(
    const float* __restrict__ feat, const float* __restrict__ W,
    float* __restrict__ proj, int n_rows)
{
    __shared__ unsigned short sWb[8 * 4 * 64 * 8];   // 16384 bf16 = 32 KB

    for (int i = threadIdx.x; i < 8 * 4 * 64 * 8; i += 256) {
        const int j  = i & 7;
        const int l  = (i >> 3) & 63;
        const int ct = (i >> 9) & 3;
        const int ks = i >> 11;
        const int k  = ks * 32 + ((l >> 4) * 8) + j;
        const int c  = ct * 16 + (l & 15);
        sWb[i] = f2bf(W[k * OUT_FEAT + c]);
    }
    __syncthreads();

    const int lane = threadIdx.x & 63;
    const int wave = threadIdx.x >> 6;
    const int row0 = blockIdx.x * 64 + wave * 16;
    if (row0 >= n_rows) return;

    const int kgrp = lane >> 4;            // 0..3
    int ar = row0 + (lane & 15);           // this lane's A row
    if (ar >= n_rows) ar = n_rows - 1;     // clamp; results discarded on store

    f32x4 fa[16];
    const float* fp = feat + (size_t)ar * IN_FEAT + kgrp * 8;
    #pragma unroll
    for (int ks = 0; ks < 8; ++ks) {
        fa[2 * ks]     = *reinterpret_cast<const f32x4*>(fp + ks * 32);
        fa[2 * ks + 1] = *reinterpret_cast<const f32x4*>(fp + ks * 32 + 4);
    }

    f32x4 acc[4];
    #pragma unroll
    for (int ct = 0; ct < 4; ++ct) acc[ct] = f32x4{0.f, 0.f, 0.f, 0.f};

    #pragma unroll
    for (int ks = 0; ks < 8; ++ks) {
        BF8 Ah, Al;
        #pragma unroll
        for (int h = 0; h < 2; ++h) {
            const f32x4 v = fa[2 * ks + h];
            #pragma unroll
            for (int j = 0; j < 4; ++j) {
                const float f = v[j];
                const unsigned short hb = f2bf(f);
                Ah.u[h * 4 + j] = hb;
                Al.u[h * 4 + j] = f2bf(f - bf2f(hb));
            }
        }
        #pragma unroll
        for (int ct = 0; ct < 4; ++ct) {
            BF8 B;
            B.v = *reinterpret_cast<const bf16x8*>(
                &sWb[((ks * 4 + ct) * 64 + lane) * 8]);
            acc[ct] = __builtin_amdgcn_mfma_f32_16x16x32_bf16(Ah.v, B.v, acc[ct], 0, 0, 0);
            acc[ct] = __builtin_amdgcn_mfma_f32_16x16x32_bf16(Al.v, B.v, acc[ct], 0, 0, 0);
        }
    }

    #pragma unroll
    for (int r = 0; r < 4; ++r) {
        const int row = row0 + kgrp * 4 + r;
        if (row < n_rows) {
            #pragma unroll
            for (int ct = 0; ct < 4; ++ct)
                proj[(size_t)row * OUT_FEAT + ct * 16 + (lane & 15)] = acc[ct][r];
        }
    }
}

// ---------------------------------------------------------------------------
// Kernel 2: out[row] += val * proj[col]  over sorted-by-row COO edges.
// One wave owns 64 contiguous edges; lane = feature column.
// Phase 1: lane i preloads edge e0+i's (r,c,v) coalesced; then a FULLY
// static-unrolled loop issues all 64 proj-row gathers into p[64] (compile-
// time readlane lane index -> SGPR col -> 64 independent global_load_dword
// outstanding, MLP=64). Phase 2: segmented register accumulation over p[i]
// with SGPR row compares; one coalesced 64-lane atomicAdd per row-segment.
// Tail (not hit: 1.6M % 64 == 0) handled by index clamp + v=0.
// ---------------------------------------------------------------------------
__global__ __launch_bounds__(256) void gather_scatter(
    const float* __restrict__ proj, const int* __restrict__ rows,
    const int* __restrict__ cols, const float* __restrict__ vals,
    float* __restrict__ out, int n_edges)
{
    const int lane = threadIdx.x & 63;
    const long wid = (long)((blockIdx.x * 256 + threadIdx.x) >> 6);
    const long e0 = wid * EPW;
    if (e0 >= n_edges) return;

    // Coalesced metadata preload: lane i <- edge e0+i (clamped for tail;
    // v forced to 0 for out-of-range lanes so their fma contributes nothing).
    const long ee = (e0 + lane < n_edges) ? (e0 + lane) : (n_edges - 1);
    const int r_v = rows[ee];
    const int c_v = cols[ee];
    const int v_bits = (e0 + lane < n_edges)
                         ? __builtin_bit_cast(int, vals[ee]) : 0;

    // Phase 1: issue all 64 gathers (static indices -> registers + full MLP).
    float p[EPW];
    #pragma unroll
    for (int i = 0; i < EPW; ++i) {
        const int c = __builtin_amdgcn_readlane(c_v, i);   // SGPR
        p[i] = proj[(size_t)c * OUT_FEAT + lane];
    }

    // Phase 2: segmented accumulate + flush.
    float acc = 0.f;
    int cur = __builtin_amdgcn_readlane(r_v, 0);
    #pragma unroll
    for (int i = 0; i < EPW; ++i) {
        const int   r = __builtin_amdgcn_readlane(r_v, i);  // SGPR
        const float v = __builtin_bit_cast(float, __builtin_amdgcn_readlane(v_bits, i));
        if (r != cur) {                                     // scalar, uniform
            atomicAdd(out + (size_t)cur * OUT_FEAT + lane, acc);
            acc = 0.f;
            cur = r;
        }
        acc = fmaf(v, p[i], acc);
    }
    atomicAdd(out + (size_t)cur * OUT_FEAT + lane, acc);
}

extern "C" void kernel_launch(void* const* d_in, const int* in_sizes, int n_in,
                              void* d_out, int out_size, void* d_ws, size_t ws_size,
                              hipStream_t stream)
{
    const float* feat     = (const float*)d_in[0];
    const float* weight   = (const float*)d_in[1];
    const int*   adj_rows = (const int*)d_in[2];
    const int*   adj_cols = (const int*)d_in[3];
    const float* adj_vals = (const float*)d_in[4];
    float*       out      = (float*)d_out;
    float*       proj     = (float*)d_ws;   // n_nodes*64*4 = 25.6 MB scratch

    const int n_nodes = in_sizes[0] / IN_FEAT;   // 100000
    const int n_edges = in_sizes[2];             // 1600000

    // out is poisoned 0xAA and nodes without edges must be 0 -> zero it
    hipMemsetAsync(d_out, 0, (size_t)out_size * sizeof(float), stream);

    const int gemm_blocks = (n_nodes + 63) / 64;
    gemm_proj_mfma<<<gemm_blocks, 256, 0, stream>>>(feat, weight, proj, n_nodes);

    const int waves  = (n_edges + EPW - 1) / EPW;
    const int blocks = (waves + 3) / 4;
    gather_scatter<<<blocks, 256, 0, stream>>>(proj, adj_rows, adj_cols,
                                               adj_vals, out, n_edges);
}

// Round 5
// 67.305 us; speedup vs baseline: 4.8493x; 1.6667x over previous
//
#include <hip/hip_runtime.h>
#include <cstdint>

#define IN_FEAT 256
#define OUT_FEAT 64

constexpr int EPW = 64;             // edges per wave in scatter (1 per lane)

typedef __attribute__((ext_vector_type(4))) float f32x4;
typedef __attribute__((ext_vector_type(8))) __bf16 bf16x8;

union BF8 { unsigned short u[8]; bf16x8 v; };

__device__ inline unsigned short f2bf(float f) {   // fp32 -> bf16 bits, RNE
    unsigned u = __builtin_bit_cast(unsigned, f);
    unsigned r = u + 0x7fffu + ((u >> 16) & 1u);
    return (unsigned short)(r >> 16);
}
__device__ inline float bf2f(unsigned short h) {
    return __builtin_bit_cast(float, (unsigned)h << 16);
}

// ---------------------------------------------------------------------------
// Kernel 1: proj(bf16) = feat @ W via mfma_f32_16x16x32_bf16.
// feat split hi/lo bf16 (2 MFMAs) -> feat quantization error cancels;
// W single bf16 staged in LDS, pre-packed into B-fragment layout:
//   sWb[((ks*4+ct)*64 + l)*8 + j] = bf16(W[ks*32 + (l>>4)*8 + j][ct*16+(l&15)])
// Prologue iterates (c, kg): at each k the 256 threads read 256 consecutive
// floats of W (fully coalesced, L2-hot); 8 k's build one 16-B LDS write.
// Block = 256 thr = 4 waves, each wave one 16-row x 64-col tile.
// ---------------------------------------------------------------------------
__global__ __launch_bounds__(256) void gemm_proj_mfma(
    const float* __restrict__ feat, const float* __restrict__ W,
    unsigned short* __restrict__ projb, int n_rows)
{
    __shared__ unsigned short sWb[8 * 4 * 64 * 8];   // 16384 bf16 = 32 KB

    {
        const int c   = threadIdx.x & 63;        // W column (coalesced axis)
        const int kg0 = threadIdx.x >> 6;        // k-group 0..3 within iter
        #pragma unroll
        for (int it = 0; it < 8; ++it) {
            const int kg = it * 4 + kg0;         // k-group 0..31 (k = kg*8+j)
            BF8 tmp;
            #pragma unroll
            for (int j = 0; j < 8; ++j)
                tmp.u[j] = f2bf(W[(kg * 8 + j) * OUT_FEAT + c]);
            const int ks = kg >> 2;
            const int l  = (kg & 3) * 16 + (c & 15);
            const int ct = c >> 4;
            *reinterpret_cast<bf16x8*>(&sWb[((ks * 4 + ct) * 64 + l) * 8]) = tmp.v;
        }
    }
    __syncthreads();

    const int lane = threadIdx.x & 63;
    const int wave = threadIdx.x >> 6;
    const int row0 = blockIdx.x * 64 + wave * 16;
    if (row0 >= n_rows) return;

    const int kgrp = lane >> 4;            // 0..3
    int ar = row0 + (lane & 15);           // this lane's A row
    if (ar >= n_rows) ar = n_rows - 1;     // clamp; results discarded on store

    // Preload full feat row-chunk: 16 outstanding dwordx4 per lane.
    f32x4 fa[16];
    const float* fp = feat + (size_t)ar * IN_FEAT + kgrp * 8;
    #pragma unroll
    for (int ks = 0; ks < 8; ++ks) {
        fa[2 * ks]     = *reinterpret_cast<const f32x4*>(fp + ks * 32);
        fa[2 * ks + 1] = *reinterpret_cast<const f32x4*>(fp + ks * 32 + 4);
    }

    f32x4 acc[4];
    #pragma unroll
    for (int ct = 0; ct < 4; ++ct) acc[ct] = f32x4{0.f, 0.f, 0.f, 0.f};

    #pragma unroll
    for (int ks = 0; ks < 8; ++ks) {
        BF8 Ah, Al;
        #pragma unroll
        for (int h = 0; h < 2; ++h) {
            const f32x4 v = fa[2 * ks + h];
            #pragma unroll
            for (int j = 0; j < 4; ++j) {
                const float f = v[j];
                const unsigned short hb = f2bf(f);
                Ah.u[h * 4 + j] = hb;
                Al.u[h * 4 + j] = f2bf(f - bf2f(hb));
            }
        }
        #pragma unroll
        for (int ct = 0; ct < 4; ++ct) {
            BF8 B;
            B.v = *reinterpret_cast<const bf16x8*>(
                &sWb[((ks * 4 + ct) * 64 + lane) * 8]);
            acc[ct] = __builtin_amdgcn_mfma_f32_16x16x32_bf16(Ah.v, B.v, acc[ct], 0, 0, 0);
            acc[ct] = __builtin_amdgcn_mfma_f32_16x16x32_bf16(Al.v, B.v, acc[ct], 0, 0, 0);
        }
    }

    #pragma unroll
    for (int r = 0; r < 4; ++r) {
        const int row = row0 + kgrp * 4 + r;
        if (row < n_rows) {
            #pragma unroll
            for (int ct = 0; ct < 4; ++ct)
                projb[(size_t)row * OUT_FEAT + ct * 16 + (lane & 15)] =
                    f2bf(acc[ct][r]);
        }
    }
}

// ---------------------------------------------------------------------------
// Kernel 2: out[row] += val * proj[col]  over sorted-by-row COO edges.
// One wave owns 64 contiguous edges; lane = feature column.
// Phase 1: lane i preloads edge e0+i's (r,c,v) coalesced; fully static-
// unrolled loop issues all 64 proj-row gathers (bf16, 128 B/row) into p[64]
// -> 64 independent loads outstanding. Phase 2: segmented register
// accumulation with SGPR row compares; one coalesced 64-lane atomicAdd per
// row-segment. Tail handled by index clamp + v=0 (1.6M % 64 == 0 anyway).
// ---------------------------------------------------------------------------
__global__ __launch_bounds__(256) void gather_scatter(
    const unsigned short* __restrict__ projb, const int* __restrict__ rows,
    const int* __restrict__ cols, const float* __restrict__ vals,
    float* __restrict__ out, int n_edges)
{
    const int lane = threadIdx.x & 63;
    const long wid = (long)((blockIdx.x * 256 + threadIdx.x) >> 6);
    const long e0 = wid * EPW;
    if (e0 >= n_edges) return;

    const long ee = (e0 + lane < n_edges) ? (e0 + lane) : (n_edges - 1);
    const int r_v = rows[ee];
    const int c_v = cols[ee];
    const int v_bits = (e0 + lane < n_edges)
                         ? __builtin_bit_cast(int, vals[ee]) : 0;

    // Phase 1: issue all 64 gathers (static indices -> registers + full MLP).
    unsigned short p[EPW];
    #pragma unroll
    for (int i = 0; i < EPW; ++i) {
        const int c = __builtin_amdgcn_readlane(c_v, i);   // SGPR
        p[i] = projb[(size_t)c * OUT_FEAT + lane];
    }

    // Phase 2: segmented accumulate + flush.
    float acc = 0.f;
    int cur = __builtin_amdgcn_readlane(r_v, 0);
    #pragma unroll
    for (int i = 0; i < EPW; ++i) {
        const int   r = __builtin_amdgcn_readlane(r_v, i);  // SGPR
        const float v = __builtin_bit_cast(float, __builtin_amdgcn_readlane(v_bits, i));
        if (r != cur) {                                     // scalar, uniform
            atomicAdd(out + (size_t)cur * OUT_FEAT + lane, acc);
            acc = 0.f;
            cur = r;
        }
        acc = fmaf(v, bf2f(p[i]), acc);
    }
    atomicAdd(out + (size_t)cur * OUT_FEAT + lane, acc);
}

extern "C" void kernel_launch(void* const* d_in, const int* in_sizes, int n_in,
                              void* d_out, int out_size, void* d_ws, size_t ws_size,
                              hipStream_t stream)
{
    const float* feat     = (const float*)d_in[0];
    const float* weight   = (const float*)d_in[1];
    const int*   adj_rows = (const int*)d_in[2];
    const int*   adj_cols = (const int*)d_in[3];
    const float* adj_vals = (const float*)d_in[4];
    float*       out      = (float*)d_out;
    unsigned short* projb = (unsigned short*)d_ws;   // n_nodes*64*2 = 12.8 MB

    const int n_nodes = in_sizes[0] / IN_FEAT;   // 100000
    const int n_edges = in_sizes[2];             // 1600000

    // out is poisoned 0xAA and nodes without edges must be 0 -> zero it
    hipMemsetAsync(d_out, 0, (size_t)out_size * sizeof(float), stream);

    const int gemm_blocks = (n_nodes + 63) / 64;
    gemm_proj_mfma<<<gemm_blocks, 256, 0, stream>>>(feat, weight, projb, n_nodes);

    const int waves  = (n_edges + EPW - 1) / EPW;
    const int blocks = (waves + 3) / 4;
    gather_scatter<<<blocks, 256, 0, stream>>>(projb, adj_rows, adj_cols,
                                               adj_vals, out, n_edges);
}

// Round 6
// 65.000 us; speedup vs baseline: 5.0212x; 1.0355x over previous
//
#include <hip/hip_runtime.h>
#include <cstdint>

#define IN_FEAT 256
#define OUT_FEAT 64

constexpr int EPW = 64;             // edges per wave in scatter (1 per lane)

typedef __attribute__((ext_vector_type(4))) float f32x4;
typedef __attribute__((ext_vector_type(8))) _Float16 f16x8;

union HF8 { _Float16 h[8]; f16x8 v; };

// ---------------------------------------------------------------------------
// Kernel 1: proj(fp16) = feat @ W via mfma_f32_16x16x32_f16.
// Single fp16 pass (10 mantissa bits) is more accurate than the previous
// bf16 hi/lo + bf16-W scheme, at half the MFMAs and ~1/3 the convert VALU
// (native _Float16 casts let the compiler emit v_cvt_pk_* packed converts).
// W staged in LDS pre-packed into B-fragment layout:
//   sWh[((ks*4+ct)*64 + l)*8 + j] = f16(W[ks*32 + (l>>4)*8 + j][ct*16+(l&15)])
// Feat loads are issued BEFORE the W prologue so HBM latency hides under it.
// Block = 256 thr = 4 waves, each wave one 16-row x 64-col tile.
// ---------------------------------------------------------------------------
__global__ __launch_bounds__(256) void gemm_proj_mfma(
    const float* __restrict__ feat, const float* __restrict__ W,
    _Float16* __restrict__ projh, int n_rows)
{
    __shared__ _Float16 sWh[8 * 4 * 64 * 8];   // 16384 fp16 = 32 KB

    const int lane = threadIdx.x & 63;
    const int wave = threadIdx.x >> 6;
    const int row0 = blockIdx.x * 64 + wave * 16;
    const int kgrp = lane >> 4;            // 0..3
    int ar = row0 + (lane & 15);           // this lane's A row
    if (ar >= n_rows) ar = n_rows - 1;     // clamp; results discarded on store

    // Phase A: issue feat row-chunk loads first (16 dwordx4 in flight).
    f32x4 fa[16];
    const float* fp = feat + (size_t)ar * IN_FEAT + kgrp * 8;
    #pragma unroll
    for (int ks = 0; ks < 8; ++ks) {
        fa[2 * ks]     = *reinterpret_cast<const f32x4*>(fp + ks * 32);
        fa[2 * ks + 1] = *reinterpret_cast<const f32x4*>(fp + ks * 32 + 4);
    }

    // Phase B: W -> fp16, packed to B-frag layout. Per j-step the 256 threads
    // read 256 consecutive floats (coalesced, L2-hot after first blocks).
    {
        const int c   = threadIdx.x & 63;        // W column (coalesced axis)
        const int kg0 = threadIdx.x >> 6;        // k-group 0..3 within iter
        #pragma unroll
        for (int it = 0; it < 8; ++it) {
            const int kg = it * 4 + kg0;         // k-group 0..31 (k = kg*8+j)
            HF8 tmp;
            #pragma unroll
            for (int j = 0; j < 8; ++j)
                tmp.h[j] = (_Float16)W[(kg * 8 + j) * OUT_FEAT + c];
            const int ks = kg >> 2;
            const int l  = (kg & 3) * 16 + (c & 15);
            const int ct = c >> 4;
            *reinterpret_cast<f16x8*>(&sWh[((ks * 4 + ct) * 64 + l) * 8]) = tmp.v;
        }
    }
    __syncthreads();
    if (row0 >= n_rows) return;            // after barrier: uniform participation

    f32x4 acc[4];
    #pragma unroll
    for (int ct = 0; ct < 4; ++ct) acc[ct] = f32x4{0.f, 0.f, 0.f, 0.f};

    #pragma unroll
    for (int ks = 0; ks < 8; ++ks) {
        HF8 A;
        #pragma unroll
        for (int h = 0; h < 2; ++h) {
            const f32x4 v = fa[2 * ks + h];
            #pragma unroll
            for (int j = 0; j < 4; ++j)
                A.h[h * 4 + j] = (_Float16)v[j];   // compiler packs: v_cvt_pk
        }
        #pragma unroll
        for (int ct = 0; ct < 4; ++ct) {
            HF8 B;
            B.v = *reinterpret_cast<const f16x8*>(
                &sWh[((ks * 4 + ct) * 64 + lane) * 8]);
            acc[ct] = __builtin_amdgcn_mfma_f32_16x16x32_f16(A.v, B.v, acc[ct], 0, 0, 0);
        }
    }

    #pragma unroll
    for (int r = 0; r < 4; ++r) {
        const int row = row0 + kgrp * 4 + r;
        if (row < n_rows) {
            #pragma unroll
            for (int ct = 0; ct < 4; ++ct)
                projh[(size_t)row * OUT_FEAT + ct * 16 + (lane & 15)] =
                    (_Float16)acc[ct][r];
        }
    }
}

// ---------------------------------------------------------------------------
// Kernel 2: out[row] += val * proj[col]  over sorted-by-row COO edges.
// One wave owns 64 contiguous edges; lane = feature column.
// Phase 1: coalesced metadata preload (lane i <- edge e0+i), then a fully
// static-unrolled loop issues all 64 fp16 proj-row gathers into p[64]
// (compile-time readlane -> SGPR col -> 64 independent loads outstanding).
// Phase 2: segmented register accumulation with SGPR row compares.
// Segments that START inside the wave (not at edge 0) and FLUSH inside the
// wave are exclusively owned (rows sorted ascending) -> plain store, no
// atomic. Only the first flush and the final flush use atomicAdd.
// ---------------------------------------------------------------------------
__global__ __launch_bounds__(256) void gather_scatter(
    const _Float16* __restrict__ projh, const int* __restrict__ rows,
    const int* __restrict__ cols, const float* __restrict__ vals,
    float* __restrict__ out, int n_edges)
{
    const int lane = threadIdx.x & 63;
    const long wid = (long)((blockIdx.x * 256 + threadIdx.x) >> 6);
    const long e0 = wid * EPW;
    if (e0 >= n_edges) return;

    const long ee = (e0 + lane < n_edges) ? (e0 + lane) : (n_edges - 1);
    const int r_v = rows[ee];
    const int c_v = cols[ee];
    const int v_bits = (e0 + lane < n_edges)
                         ? __builtin_bit_cast(int, vals[ee]) : 0;

    // Phase 1: issue all 64 gathers (static indices -> registers, full MLP).
    _Float16 p[EPW];
    #pragma unroll
    for (int i = 0; i < EPW; ++i) {
        const int c = __builtin_amdgcn_readlane(c_v, i);   // SGPR
        p[i] = projh[(size_t)c * OUT_FEAT + lane];
    }

    // Phase 2: segmented accumulate + flush.
    float acc = 0.f;
    int cur = __builtin_amdgcn_readlane(r_v, 0);
    bool first_seg = true;                                  // uniform
    #pragma unroll
    for (int i = 0; i < EPW; ++i) {
        const int   r = __builtin_amdgcn_readlane(r_v, i);  // SGPR
        const float v = __builtin_bit_cast(float, __builtin_amdgcn_readlane(v_bits, i));
        if (r != cur) {                                     // scalar, uniform
            float* dst = out + (size_t)cur * OUT_FEAT + lane;
            if (first_seg) atomicAdd(dst, acc);             // may span waves
            else           *dst = acc;                      // exclusive row
            first_seg = false;
            acc = 0.f;
            cur = r;
        }
        acc = fmaf(v, (float)p[i], acc);
    }
    atomicAdd(out + (size_t)cur * OUT_FEAT + lane, acc);    // may span waves
}

extern "C" void kernel_launch(void* const* d_in, const int* in_sizes, int n_in,
                              void* d_out, int out_size, void* d_ws, size_t ws_size,
                              hipStream_t stream)
{
    const float* feat     = (const float*)d_in[0];
    const float* weight   = (const float*)d_in[1];
    const int*   adj_rows = (const int*)d_in[2];
    const int*   adj_cols = (const int*)d_in[3];
    const float* adj_vals = (const float*)d_in[4];
    float*       out      = (float*)d_out;
    _Float16*    projh    = (_Float16*)d_ws;   // n_nodes*64*2 = 12.8 MB

    const int n_nodes = in_sizes[0] / IN_FEAT;   // 100000
    const int n_edges = in_sizes[2];             // 1600000

    // out is poisoned 0xAA and nodes without edges must be 0 -> zero it
    hipMemsetAsync(d_out, 0, (size_t)out_size * sizeof(float), stream);

    const int gemm_blocks = (n_nodes + 63) / 64;
    gemm_proj_mfma<<<gemm_blocks, 256, 0, stream>>>(feat, weight, projh, n_nodes);

    const int waves  = (n_edges + EPW - 1) / EPW;
    const int blocks = (waves + 3) / 4;
    gather_scatter<<<blocks, 256, 0, stream>>>(projh, adj_rows, adj_cols,
                                               adj_vals, out, n_edges);
}